// Round 5
// baseline (291.784 us; speedup 1.0000x reference)
//
#include <hip/hip_runtime.h>
#include <math.h>

typedef _Float16 half8   __attribute__((ext_vector_type(8)));
typedef _Float16 half2v  __attribute__((ext_vector_type(2)));
typedef float    float4v __attribute__((ext_vector_type(4)));

constexpr int T_ = 1 << 18;            // hash table size per level
constexpr unsigned TMASK = T_ - 1;
constexpr unsigned PRIME = 2654435761u;
constexpr int HP = 72;                 // H row pitch in f16 (64 + 8 pad)
constexpr int MAXE = 4352;             // LDS subtable capacity (actual ~4174 entries)

// ws layout:
//   [0, 22528)      : 22 W-fragments (f16), 64 lanes x 8 halfs each
//   [22528, ...)    : fp32: biases b1[64] b2[64] b3[64] b4pad[16] | N_values[16] | offs[16]
constexpr int WFRAG_HALFS = 22 * 64 * 8;
constexpr int BIAS_FLOATS = 208;
constexpr int WS_FLOATS   = 240;                 // 208 bias + 16 nv + 16 off
constexpr int WS_BYTES    = 22528 + WS_FLOATS * 4;  // 23488
constexpr int WS_UINT4    = WS_BYTES / 16;          // 1468

struct NVals { float n[16]; };
struct FOffs { float o[16]; };

// ---------------- prep: swizzle weights into MFMA fragment order ----------------
__global__ void prep_weights(const float* __restrict__ W1, const float* __restrict__ b1,
                             const float* __restrict__ W2, const float* __restrict__ b2,
                             const float* __restrict__ W3, const float* __restrict__ b3,
                             const float* __restrict__ W4, const float* __restrict__ b4,
                             _Float16* __restrict__ wsW, float* __restrict__ wsB,
                             NVals nv, FOffs fo)
{
    const int tid = threadIdx.x;
    // weights-as-A (transposed form): lane l holds W[k=32s+8*(l>>4)+j][n=16t+(l&15)]
    for (int e = tid; e < WFRAG_HALFS; e += 256) {
        const int frag = e >> 9;
        const int l    = (e >> 3) & 63;
        const int j    = e & 7;
        const int g = l >> 4, m = l & 15;
        float v;
        if (frag < 4) {
            v = W1[(8*g + j) * 64 + 16*frag + m];
        } else if (frag < 12) {
            const int s = (frag - 4) >> 2, t = (frag - 4) & 3;
            v = W2[(32*s + 8*g + j) * 64 + 16*t + m];
        } else if (frag < 20) {
            const int s = (frag - 12) >> 2, t = (frag - 12) & 3;
            v = W3[(32*s + 8*g + j) * 64 + 16*t + m];
        } else {
            const int s = frag - 20;
            v = (m < 3) ? W4[(32*s + 8*g + j) * 3 + m] : 0.f;
        }
        wsW[e] = (_Float16)v;
    }
    if (tid < 64) { wsB[tid] = b1[tid]; wsB[64 + tid] = b2[tid]; wsB[128 + tid] = b3[tid]; }
    if (tid >= 64 && tid < 80) { const int r = tid - 64; wsB[192 + r] = (r < 3) ? b4[r] : 0.f; }
    if (tid >= 80 && tid < 96)  wsB[BIAS_FLOATS + (tid - 80)] = nv.n[tid - 80];
    if (tid >= 96 && tid < 112) wsB[224 + (tid - 96)] = fo.o[tid - 96];
}

// ---------------- main fused kernel ----------------
// Block = 256 = 4 waves; each wave does 4 tiles of 16 points. Transposed MFMA:
// activations ride B-operand (B[n=pt][k]), weights ride A. Encoder writes its
// lane's B-fragment directly. Gather-traffic fix (round 5): corners (0,0) and
// (xf,0) live in entries [0, N_l) of each level -> staged to an LDS f16 subtable
// once per block; only the 2 random-hash corners go to global => halves the
// divergent global lane-requests (the round-4 L1-pipe bottleneck).
#define DS_FENCE() __asm__ volatile("s_waitcnt lgkmcnt(0)" ::: "memory")

__global__ __launch_bounds__(256, 2)
void fused_hashnerf_mfma(const float2* __restrict__ X,
                         const float2* __restrict__ table,
                         const uint4* __restrict__ ws,
                         float* __restrict__ out,
                         NVals nv)
{
    __shared__ uint4    sRaw[WS_UINT4];
    __shared__ _Float16 sH[4][16 * HP];
    __shared__ half2v   sT[MAXE];          // per-level entries [0, N_l), f16 pairs

    const int tid = threadIdx.x;
    for (int i = tid; i < WS_UINT4; i += 256) sRaw[i] = ws[i];

    // stage subtable (coalesced; l unrolled so nv indexing is constant)
    {
        int off = 0;
        #pragma unroll
        for (int l = 0; l < 16; ++l) {
            const int nl = (int)nv.n[l];
            const float2* tl = table + (size_t)l * T_;
            for (int i = tid; i < nl; i += 256) {
                const float2 v = tl[i];
                sT[off + i] = half2v{(_Float16)v.x, (_Float16)v.y};
            }
            off += nl;
        }
    }
    __syncthreads();

    const _Float16* Wl = (const _Float16*)sRaw;
    const float*    Bl = (const float*)(sRaw + (22528 / 16));

    const int wave = tid >> 6, lane = tid & 63;
    const int g = lane >> 4, c = lane & 15;
    _Float16* H = &sH[wave][0];

    float4v b1f[4], b2f[4], b3f[4], b4f;
    #pragma unroll
    for (int t = 0; t < 4; ++t) {
        b1f[t] = *(const float4v*)(Bl +       16*t + 4*g);
        b2f[t] = *(const float4v*)(Bl +  64 + 16*t + 4*g);
        b3f[t] = *(const float4v*)(Bl + 128 + 16*t + 4*g);
    }
    b4f = *(const float4v*)(Bl + 192 + 4*g);

    // per-lane level constants (levels 4g..4g+3)
    float nvq[4]; int offq[4]; const float2* tq[4];
    float v0x[4], v0y[4];
    #pragma unroll
    for (int q = 0; q < 4; ++q) {
        nvq[q]  = Bl[BIAS_FLOATS + 4*g + q];
        offq[q] = (int)Bl[224 + 4*g + q];
        tq[q]   = table + (size_t)(4*g + q) * T_;
        const half2v h0 = sT[offq[q]];      // corner (0,0): point-invariant!
        v0x[q] = (float)h0.x; v0y[q] = (float)h0.y;
    }

    const int base_pt = blockIdx.x * 256 + wave * 64;

    for (int it = 0; it < 4; ++it) {
        const int p = base_pt + it * 16 + c;
        const float2 xy = X[p];

        // ---- phase 1: hashes for all 4 levels ----
        float fxq[4], fyq[4]; int xiq[4]; unsigned i1[4], i3[4];
        #pragma unroll
        for (int q = 0; q < 4; ++q) {
            const float n = nvq[q];
            const float xs = xy.x * n, ys = xy.y * n;
            const float xf = floorf(xs), yf = floorf(ys);
            fxq[q] = xs - xf; fyq[q] = ys - yf;
            const unsigned xi = (unsigned)(int)xf, yi = (unsigned)(int)yf;
            const unsigned yp = yi * PRIME;
            xiq[q] = (int)xi;
            i1[q] = yp & TMASK;            // corner (0, yf)  — random
            i3[q] = (xi ^ yp) & TMASK;     // corner (xf, yf) — random
        }
        // ---- phase 2: issue all gathers (global v1,v3 ; LDS v2) ----
        float2 g1[4], g3[4]; half2v l2[4];
        #pragma unroll
        for (int q = 0; q < 4; ++q) {
            g1[q] = tq[q][i1[q]];
            g3[q] = tq[q][i3[q]];
            l2[q] = sT[offq[q] + xiq[q]];  // corner (xf,0): xi < N_l
        }
        // ---- phase 3: bilinear blend -> B-fragment ----
        half8 feat;
        #pragma unroll
        for (int q = 0; q < 4; ++q) {
            const float fx = fxq[q], fy = fyq[q];
            const float cx = 1.f - fx, cy = 1.f - fy;
            const float w0 = cx*cy, w1 = cx*fy, w2 = fx*cy, w3 = fx*fy;
            feat[2*q+0] = (_Float16)(w0*v0x[q] + w1*g1[q].x + w2*(float)l2[q].x + w3*g3[q].x);
            feat[2*q+1] = (_Float16)(w0*v0y[q] + w1*g1[q].y + w2*(float)l2[q].y + w3*g3[q].y);
        }

        // ---- L1 ----
        float4v acc[4];
        #pragma unroll
        for (int t = 0; t < 4; ++t) {
            const half8 wf = *(const half8*)(Wl + (t*64 + lane)*8);
            acc[t] = __builtin_amdgcn_mfma_f32_16x16x32_f16(wf, feat, b1f[t], 0, 0, 0);
        }
        #pragma unroll
        for (int t = 0; t < 4; ++t) {
            union { _Float16 h[4]; float2 f2; } u;
            #pragma unroll
            for (int r = 0; r < 4; ++r) {
                const float v = acc[t][r];
                u.h[r] = (_Float16)(v > 0.f ? v : 0.01f * v);
            }
            *(float2*)(H + c*HP + 16*t + 4*g) = u.f2;
        }
        DS_FENCE();

        // ---- L2 ----
        half8 a0 = *(const half8*)(H + c*HP +      8*g);
        half8 a1 = *(const half8*)(H + c*HP + 32 + 8*g);
        float4v acc2[4];
        #pragma unroll
        for (int t = 0; t < 4; ++t) {
            const half8 w0f = *(const half8*)(Wl + ((4 + t)*64 + lane)*8);
            const half8 w1f = *(const half8*)(Wl + ((8 + t)*64 + lane)*8);
            float4v a = __builtin_amdgcn_mfma_f32_16x16x32_f16(w0f, a0, b2f[t], 0, 0, 0);
            acc2[t]   = __builtin_amdgcn_mfma_f32_16x16x32_f16(w1f, a1, a,      0, 0, 0);
        }
        #pragma unroll
        for (int t = 0; t < 4; ++t) {
            union { _Float16 h[4]; float2 f2; } u;
            #pragma unroll
            for (int r = 0; r < 4; ++r) {
                const float v = acc2[t][r];
                u.h[r] = (_Float16)(v > 0.f ? v : 0.01f * v);
            }
            *(float2*)(H + c*HP + 16*t + 4*g) = u.f2;
        }
        DS_FENCE();

        // ---- L3 ----
        a0 = *(const half8*)(H + c*HP +      8*g);
        a1 = *(const half8*)(H + c*HP + 32 + 8*g);
        float4v acc3[4];
        #pragma unroll
        for (int t = 0; t < 4; ++t) {
            const half8 w0f = *(const half8*)(Wl + ((12 + t)*64 + lane)*8);
            const half8 w1f = *(const half8*)(Wl + ((16 + t)*64 + lane)*8);
            float4v a = __builtin_amdgcn_mfma_f32_16x16x32_f16(w0f, a0, b3f[t], 0, 0, 0);
            acc3[t]   = __builtin_amdgcn_mfma_f32_16x16x32_f16(w1f, a1, a,      0, 0, 0);
        }
        #pragma unroll
        for (int t = 0; t < 4; ++t) {
            union { _Float16 h[4]; float2 f2; } u;
            #pragma unroll
            for (int r = 0; r < 4; ++r) {
                const float v = acc3[t][r];
                u.h[r] = (_Float16)(v > 0.f ? v : 0.01f * v);
            }
            *(float2*)(H + c*HP + 16*t + 4*g) = u.f2;
        }
        DS_FENCE();

        // ---- L4 ----
        a0 = *(const half8*)(H + c*HP +      8*g);
        a1 = *(const half8*)(H + c*HP + 32 + 8*g);
        const half8 w40 = *(const half8*)(Wl + (20*64 + lane)*8);
        const half8 w41 = *(const half8*)(Wl + (21*64 + lane)*8);
        float4v o = __builtin_amdgcn_mfma_f32_16x16x32_f16(w40, a0, b4f, 0, 0, 0);
        o         = __builtin_amdgcn_mfma_f32_16x16x32_f16(w41, a1, o,   0, 0, 0);
        if (g == 0) {
            float* op = out + (size_t)3 * p;
            op[0] = fmaxf(o[0], 0.f);
            op[1] = fmaxf(o[1], 0.f);
            op[2] = fmaxf(o[2], 0.f);
        }
    }
}

extern "C" void kernel_launch(void* const* d_in, const int* in_sizes, int n_in,
                              void* d_out, int out_size, void* d_ws, size_t ws_size,
                              hipStream_t stream) {
    const float2* X     = (const float2*)d_in[0];
    const float2* table = (const float2*)d_in[1];
    const float*  W1    = (const float*)d_in[2];
    const float*  b1    = (const float*)d_in[3];
    const float*  W2    = (const float*)d_in[4];
    const float*  b2    = (const float*)d_in[5];
    const float*  W3    = (const float*)d_in[6];
    const float*  b3    = (const float*)d_in[7];
    const float*  W4    = (const float*)d_in[8];
    const float*  b4    = (const float*)d_in[9];
    float* out          = (float*)d_out;

    const int npts = in_sizes[0] / 2;

    // N_l = floor(float32(16 * b^l)), b in double (matches numpy); offs = prefix sum
    NVals nv; FOffs fo;
    const double bg = exp((log(1024.0) - log(16.0)) / 15.0);
    int off = 0;
    for (int l = 0; l < 16; ++l) {
        nv.n[l] = floorf((float)(16.0 * pow(bg, (double)l)));
        fo.o[l] = (float)off;
        off += (int)nv.n[l];
    }

    _Float16* wsW = (_Float16*)d_ws;
    float*    wsB = (float*)((char*)d_ws + 22528);

    prep_weights<<<1, 256, 0, stream>>>(W1, b1, W2, b2, W3, b3, W4, b4, wsW, wsB, nv, fo);
    fused_hashnerf_mfma<<<npts / 256, 256, 0, stream>>>(X, table, (const uint4*)d_ws, out, nv);
}